// Round 14
// baseline (68.367 us; speedup 1.0000x reference)
//
#include <hip/hip_runtime.h>

#define N_ATOMS 8388608
#define N_MOLS  262144
#define N_PAIRS (N_ATOMS / 2)        // 4194304 pairs
#define HALF    (N_PAIRS / 2)        // 2097152 threads in pass1
#define NCHUNKS (N_PAIRS / 64)       // 65536 wave-chunks of 128 atoms
#define SLOTS   32                   // entry window per chunk
#define NSLOT   (NCHUNKS * SLOTS)    // 2M slots

// DPP cross-lane helpers (VALU-only). Masked/invalid lanes keep `old`:
// key old=-1 (never matches), value old=0.
template<int CTRL, int RM>
__device__ __forceinline__ int dpp_key(int v) {
    return __builtin_amdgcn_update_dpp(-1, v, CTRL, RM, 0xf, false);
}
template<int CTRL, int RM>
__device__ __forceinline__ float dpp_val(float v) {
    return __int_as_float(
        __builtin_amdgcn_update_dpp(0, __float_as_int(v), CTRL, RM, 0xf, false));
}

// One 128-atom wave-chunk. NO scattered writes to the (cross-XCD-shared)
// sum arrays: every segment partial becomes an entry in this chunk's
// PRIVATE 32-slot window (one wave per window -> no cross-XCD line sharing;
// rank-compacted -> near-coalesced). Entries:
//   - "orphan": atom0 of a boundary pair (its molecule's run ends there);
//   - "tail":   segment tail of the post-combine DPP scan.
// Overflow (>32 segments; needs molecules <=4 atoms -- effectively never,
// sizes ~Poisson(32)) falls back to direct atomics for correctness.
__device__ __forceinline__ void process_chunk(
    float4 hv, float2 qv, int2 mv, int lane, int chunkId,
    float* __restrict__ sum_qe, float* __restrict__ sum_si,
    int* __restrict__ ikey, float2* __restrict__ ival, int* __restrict__ cnt)
{
    float si0 = 1.0f / hv.y, si1 = 1.0f / hv.w;
    float qe0 = qv.x + hv.x * si0, qe1 = qv.y + hv.z * si1;
    bool  b   = (mv.x != mv.y);          // pair straddles a boundary
    int   key = mv.y;                    // post-combine key
    float pq  = b ? qe1 : (qe0 + qe1);
    float ps  = b ? si1 : (si0 + si1);

    // 6-step DPP segmented inclusive scan over (key, pq, ps)
#define SCAN_STEP(CTRL, RM)                                 \
    {                                                       \
        int   k  = dpp_key<CTRL, RM>(key);                  \
        float vq = dpp_val<CTRL, RM>(pq);                   \
        float vs = dpp_val<CTRL, RM>(ps);                   \
        if (k == key) { pq += vq; ps += vs; }               \
    }
    SCAN_STEP(0x111, 0xf)   // row_shr:1
    SCAN_STEP(0x112, 0xf)   // row_shr:2
    SCAN_STEP(0x114, 0xf)   // row_shr:4
    SCAN_STEP(0x118, 0xf)   // row_shr:8
    SCAN_STEP(0x142, 0xa)   // row_bcast:15 -> rows 1,3
    SCAN_STEP(0x143, 0xc)   // row_bcast:31 -> rows 2,3
#undef SCAN_STEP

    int  nk = __shfl_down(key, 1, 64);
    bool isTail = (lane == 63) || (nk != key);

    unsigned long long om = __ballot(b);
    unsigned long long tm = __ballot(isTail);
    unsigned long long below = (1ull << lane) - 1ull;   // lane 0 -> 0
    int no    = __popcll(om);
    int orank = __popcll(om & below);
    int trank = no + __popcll(tm & below);
    int base  = chunkId * SLOTS;

    if (b) {
        if (orank < SLOTS) {
            ikey[base + orank] = mv.x;
            ival[base + orank] = make_float2(qe0, si0);
        } else {
            unsafeAtomicAdd(&sum_qe[mv.x], qe0);
            unsafeAtomicAdd(&sum_si[mv.x], si0);
        }
    }
    if (isTail) {
        if (trank < SLOTS) {
            ikey[base + trank] = key;
            ival[base + trank] = make_float2(pq, ps);
        } else {
            unsafeAtomicAdd(&sum_qe[key], pq);
            unsafeAtomicAdd(&sum_si[key], ps);
        }
    }
    if (lane == 0) {
        int tot = no + __popcll(tm);
        cnt[chunkId] = tot < SLOTS ? tot : SLOTS;
    }
}

// Pass 1: 2 wave-chunks per wave (A at g, B at g+HALF), coalesced loads
// (h: float4/lane, q: float2, mol: int2). No scattered sum-array writes.
__global__ __launch_bounds__(256) void ce_pass1(
    const float4* __restrict__ h4, const float2* __restrict__ q2,
    const int2* __restrict__ mol2,
    float* __restrict__ sum_qe, float* __restrict__ sum_si,
    int* __restrict__ ikey, float2* __restrict__ ival, int* __restrict__ cnt)
{
    const int g = blockIdx.x * blockDim.x + threadIdx.x;   // 0 .. HALF-1
    const int lane = threadIdx.x & 63;
    const int chunkA = g >> 6;
    const int chunkB = chunkA + (NCHUNKS / 2);

    float4 hA = h4[g];       float4 hB = h4[g + HALF];
    float2 qA = q2[g];       float2 qB = q2[g + HALF];
    int2   mA = mol2[g];     int2   mB = mol2[g + HALF];

    process_chunk(hA, qA, mA, lane, chunkA, sum_qe, sum_si, ikey, ival, cnt);
    process_chunk(hB, qB, mB, lane, chunkB, sum_qe, sum_si, ikey, ival, cnt);
}

// Merge: thread per slot; valid prefix per the chunk count; ~590K scattered
// atomics in a tiny dedicated kernel (proven-cheap pattern, ~3-5us).
__global__ __launch_bounds__(256) void ce_merge(
    const int* __restrict__ ikey, const float2* __restrict__ ival,
    const int* __restrict__ cnt,
    float* __restrict__ sum_qe, float* __restrict__ sum_si)
{
    int i = blockIdx.x * 256 + threadIdx.x;   // 0 .. NSLOT-1
    int c = cnt[i >> 5];                      // SLOTS = 32
    if ((i & 31) < c) {
        int k = ikey[i];
        float2 v = ival[i];
        unsafeAtomicAdd(&sum_qe[k], v.x);
        unsafeAtomicAdd(&sum_si[k], v.y);
    }
}

// Pass 2: t = sum_qe / sum_si
__global__ __launch_bounds__(256) void ce_pass2(
    const float* __restrict__ sum_qe, const float* __restrict__ sum_si,
    float* __restrict__ t)
{
    int m = blockIdx.x * blockDim.x + threadIdx.x;
    t[m] = sum_qe[m] / sum_si[m];
}

// Pass 3: 4 atoms/thread, coalesced mol/out; t gather sorted + L2-resident.
__global__ __launch_bounds__(256) void ce_pass3(
    const float4* __restrict__ h4, const int4* __restrict__ mol4,
    const float* __restrict__ tmol, float4* __restrict__ out4)
{
    int g = blockIdx.x * 256 + threadIdx.x;   // over N_ATOMS/4
    int4   m4 = mol4[g];
    float4 hA = h4[g * 2];
    float4 hB = h4[g * 2 + 1];
    float4 o;
    o.x = (tmol[m4.x] - hA.x) / hA.y;
    o.y = (tmol[m4.y] - hA.z) / hA.w;
    o.z = (tmol[m4.z] - hB.x) / hB.y;
    o.w = (tmol[m4.w] - hB.z) / hB.w;
    out4[g] = o;
}

extern "C" void kernel_launch(void* const* d_in, const int* in_sizes, int n_in,
                              void* d_out, int out_size, void* d_ws, size_t ws_size,
                              hipStream_t stream) {
    const float4* h4   = (const float4*)d_in[0];
    const float2* q2   = (const float2*)d_in[1];
    const int2*   mol2 = (const int2*)d_in[2];
    const int4*   mol4 = (const int4*)d_in[2];
    float4* out4 = (float4*)d_out;

    float*  sum_qe = (float*)d_ws;                       // 1 MB
    float*  sum_si = sum_qe + N_MOLS;                    // 1 MB
    float*  tmol   = sum_si + N_MOLS;                    // 1 MB
    int*    cnt    = (int*)(tmol + N_MOLS);              // 256 KB
    int*    ikey   = cnt + NCHUNKS;                      // 8 MB
    float2* ival   = (float2*)(ikey + NSLOT);            // 16 MB (8B-aligned)

    // zero only the sum arrays (cnt fully written; windows prefix-guarded)
    hipMemsetAsync(d_ws, 0, (size_t)2 * N_MOLS * sizeof(float), stream);

    ce_pass1<<<HALF / 256, 256, 0, stream>>>(h4, q2, mol2, sum_qe, sum_si,
                                             ikey, ival, cnt);
    ce_merge<<<NSLOT / 256, 256, 0, stream>>>(ikey, ival, cnt, sum_qe, sum_si);
    ce_pass2<<<N_MOLS / 256, 256, 0, stream>>>(sum_qe, sum_si, tmol);
    ce_pass3<<<N_ATOMS / 4 / 256, 256, 0, stream>>>(h4, mol4, tmol, out4);
}

// Round 15
// 38.733 us; speedup vs baseline: 1.7651x; 1.7651x over previous
//
#include <hip/hip_runtime.h>

#define N_ATOMS 8388608
#define N_MOLS  262144
#define N_PAIRS (N_ATOMS / 2)          // 4194304
#define TPB     256
#define PPB     512                    // pairs per block (2 per thread)
#define APB     1024                   // atoms per block
#define NBLK    (N_PAIRS / PPB)        // 8192 blocks
#define NBOUND  (NBLK - 1)             // 8191 boundaries
#define BINS    1280                   // block mol-span 1024 + 256 id-gap slack

// DPP cross-lane helpers (VALU-only). Masked/invalid lanes keep `old`:
// key old=-1 (never matches), value old=0.
template<int CTRL, int RM>
__device__ __forceinline__ int dpp_key(int v) {
    return __builtin_amdgcn_update_dpp(-1, v, CTRL, RM, 0xf, false);
}
template<int CTRL, int RM>
__device__ __forceinline__ float dpp_val(float v) {
    return __int_as_float(
        __builtin_amdgcn_update_dpp(0, __float_as_int(v), CTRL, RM, 0xf, false));
}

// Main kernel: per-block segment sums entirely in LDS bins, then t, then a
// DENSE UNCONDITIONAL coalesced output write for every atom. No global
// scatter, no global atomics, no global memset dependencies.
__global__ __launch_bounds__(TPB) void ce_main(
    const float4* __restrict__ h4, const float2* __restrict__ q2,
    const int2* __restrict__ mol2, float2* __restrict__ out2,
    int* __restrict__ headKey, float2* __restrict__ headVal,
    int* __restrict__ headEnd,
    int* __restrict__ tailKey, float2* __restrict__ tailVal,
    int* __restrict__ tailStart, int* __restrict__ flags)
{
    __shared__ float bq[BINS], bs[BINS];
    __shared__ int sFirst, sLast, sHeadEnd, sTailStart;

    const int t = threadIdx.x;
    const int lane = t & 63;
    const int B = blockIdx.x;
    const int pbase = B * PPB;
    const int p0 = pbase + t, p1 = pbase + TPB + t;

    // issue all global loads first (latency overlap with LDS init)
    float4 h0 = h4[p0], h1 = h4[p1];
    float2 q0 = q2[p0], q1 = q2[p1];
    int2   m0 = mol2[p0], m1 = mol2[p1];

    for (int i = t; i < BINS; i += TPB) { bq[i] = 0.f; bs[i] = 0.f; }
    if (t == 0) { sFirst = m0.x; sHeadEnd = -1; sTailStart = 0x7fffffff; }
    if (t == TPB - 1) sLast = m1.y;
    __syncthreads();
    const int mF = sFirst, mL = sLast;
    const bool bad = (mL - mF >= BINS);   // id-gap overflow (never in practice)

    float si00, esi00, si01, esi01, si10, esi10, si11, esi11;

#define CHUNK(hv, qv, mv, PIDX, SI0, ESI0, SI1, ESI1)                        \
    {                                                                        \
        float si0 = 1.0f / hv.y, si1 = 1.0f / hv.w;                          \
        float esi0 = hv.x * si0, esi1 = hv.z * si1;                          \
        float qe0 = qv.x + esi0, qe1 = qv.y + esi1;                          \
        bool  b = (mv.x != mv.y);                                            \
        int   key = mv.y;                                                    \
        float pq = b ? qe1 : (qe0 + qe1);                                    \
        float ps = b ? si1 : (si0 + si1);                                    \
        if (b) {                                                             \
            int idx = min(mv.x - mF, BINS - 1);                              \
            atomicAdd(&bq[idx], qe0); atomicAdd(&bs[idx], si0);              \
        }                                                                    \
        SCAN_STEP(0x111, 0xf) SCAN_STEP(0x112, 0xf)                          \
        SCAN_STEP(0x114, 0xf) SCAN_STEP(0x118, 0xf)                          \
        SCAN_STEP(0x142, 0xa) SCAN_STEP(0x143, 0xc)                          \
        int  nk = __shfl_down(key, 1, 64);                                   \
        bool tail = (lane == 63) || (nk != key);                             \
        if (tail) {                                                          \
            int idx = min(key - mF, BINS - 1);                               \
            atomicAdd(&bq[idx], pq); atomicAdd(&bs[idx], ps);                \
        }                                                                    \
        int a0 = (PIDX) * 2;                                                 \
        if (mv.y == mF)      atomicMax(&sHeadEnd, a0 + 1);                   \
        else if (mv.x == mF) atomicMax(&sHeadEnd, a0);                       \
        if (mv.x == mL)      atomicMin(&sTailStart, a0);                     \
        else if (mv.y == mL) atomicMin(&sTailStart, a0 + 1);                 \
        SI0 = si0; ESI0 = esi0; SI1 = si1; ESI1 = esi1;                      \
    }
#define SCAN_STEP(CTRL, RM)                                                  \
    {                                                                        \
        int   k  = dpp_key<CTRL, RM>(key);                                   \
        float vq = dpp_val<CTRL, RM>(pq);                                    \
        float vs = dpp_val<CTRL, RM>(ps);                                    \
        if (k == key) { pq += vq; ps += vs; }                                \
    }

    CHUNK(h0, q0, m0, p0, si00, esi00, si01, esi01)
    CHUNK(h1, q1, m1, p1, si10, esi10, si11, esi11)
#undef SCAN_STEP
#undef CHUNK

    __syncthreads();
    // export records (reads of bq/bs complete before the divide overwrites)
    if (t == 0) {
        headKey[B] = mF;
        headVal[B] = make_float2(bq[0], bs[0]);
        headEnd[B] = sHeadEnd;
        flags[B]   = bad ? 1 : 0;
    }
    if (t == 64) {
        int li = min(mL - mF, BINS - 1);
        tailKey[B]   = mL;
        tailVal[B]   = make_float2(bq[li], bs[li]);
        tailStart[B] = sTailStart;
    }
    __syncthreads();
    for (int i = t; i < BINS; i += TPB) bq[i] = bq[i] / bs[i];  // t per bin
    __syncthreads();

    int i00 = min(m0.x - mF, BINS - 1), i01 = min(m0.y - mF, BINS - 1);
    int i10 = min(m1.x - mF, BINS - 1), i11 = min(m1.y - mF, BINS - 1);
    out2[p0] = make_float2(bq[i00] * si00 - esi00, bq[i01] * si01 - esi01);
    out2[p1] = make_float2(bq[i10] * si10 - esi10, bq[i11] * si11 - esi11);
}

// Cleanup: one wave per block boundary; merge the straddling molecule's
// records along its (<=2-block, guarded longer) chain and rewrite its atoms.
__global__ __launch_bounds__(TPB) void ce_cleanup(
    const float2* __restrict__ h2, float* __restrict__ out,
    const int* __restrict__ headKey, const float2* __restrict__ headVal,
    const int* __restrict__ headEnd,
    const int* __restrict__ tailKey, const float2* __restrict__ tailVal,
    const int* __restrict__ tailStart)
{
    int i = blockIdx.x * 4 + (threadIdx.x >> 6);   // boundary id
    if (i >= NBOUND) return;
    int lane = threadIdx.x & 63;

    int M = tailKey[i];
    if (headKey[i + 1] != M) return;               // no straddler here
    if (headKey[i] == M && i > 0 && tailKey[i - 1] == M) return;  // left-owned

    float2 tot = tailVal[i];
    int start = tailStart[i];
    int j = i + 1;
    float2 hv1 = headVal[j];
    tot.x += hv1.x; tot.y += hv1.y;
    while (j < NBOUND && tailKey[j] == M && headKey[j + 1] == M) {
        ++j;
        float2 hvj = headVal[j];
        tot.x += hvj.x; tot.y += hvj.y;
    }
    int end = headEnd[j];
    float tt = tot.x / tot.y;
    for (int a = start + lane; a <= end; a += 64) {
        float2 hv = h2[a];
        out[a] = (tt - hv.x) / hv.y;
    }
}

// Repair: dead-code safety net for bin-span overflow (id-gap pathology).
// Rewrites every molecule overlapping a flagged block by direct walk.
__global__ __launch_bounds__(TPB) void ce_repair(
    const float2* __restrict__ h2, const float* __restrict__ q,
    const int* __restrict__ mol, float* __restrict__ out,
    const int* __restrict__ flags)
{
    for (int fb = blockIdx.x * 32; fb < blockIdx.x * 32 + 32; ++fb) {
        if (!flags[fb]) continue;
        int bStart = fb * APB;
        // head molecule may start in an earlier block
        if (threadIdx.x == 0) {
            int s = bStart;
            while (s > 0 && mol[s - 1] == mol[bStart]) --s;
            if (s < bStart) {
                int m = mol[s];
                float sq = 0.f, ss = 0.f; int e = s;
                for (int x = s; x < N_ATOMS && mol[x] == m; ++x) {
                    float2 hv = h2[x]; float si = 1.0f / hv.y;
                    sq += q[x] + hv.x * si; ss += si; e = x;
                }
                float tt = sq / ss;
                for (int x = s; x <= e; ++x) {
                    float2 hv = h2[x]; out[x] = (tt - hv.x) / hv.y;
                }
            }
        }
        for (int a = bStart + threadIdx.x; a < bStart + APB; a += TPB) {
            if (a != 0 && mol[a - 1] == mol[a]) continue;   // not a mol start
            int m = mol[a];
            float sq = 0.f, ss = 0.f; int e = a;
            for (int x = a; x < N_ATOMS && mol[x] == m; ++x) {
                float2 hv = h2[x]; float si = 1.0f / hv.y;
                sq += q[x] + hv.x * si; ss += si; e = x;
            }
            float tt = sq / ss;
            for (int x = a; x <= e; ++x) {
                float2 hv = h2[x]; out[x] = (tt - hv.x) / hv.y;
            }
        }
    }
}

extern "C" void kernel_launch(void* const* d_in, const int* in_sizes, int n_in,
                              void* d_out, int out_size, void* d_ws, size_t ws_size,
                              hipStream_t stream) {
    const float4* h4   = (const float4*)d_in[0];
    const float2* h2   = (const float2*)d_in[0];
    const float*  q    = (const float*)d_in[1];
    const float2* q2   = (const float2*)d_in[1];
    const int*    mol  = (const int*)d_in[2];
    const int2*   mol2 = (const int2*)d_in[2];
    float2* out2 = (float2*)d_out;
    float*  out  = (float*)d_out;

    // ws layout (8B-aligned first)
    float2* headVal   = (float2*)d_ws;                 // 64 KB
    float2* tailVal   = headVal + NBLK;                // 64 KB
    int*    headKey   = (int*)(tailVal + NBLK);        // 32 KB
    int*    tailKey   = headKey + NBLK;                // 32 KB
    int*    headEnd   = tailKey + NBLK;                // 32 KB
    int*    tailStart = headEnd + NBLK;                // 32 KB
    int*    flags     = tailStart + NBLK;              // 32 KB

    ce_main<<<NBLK, TPB, 0, stream>>>(h4, q2, mol2, out2,
                                      headKey, headVal, headEnd,
                                      tailKey, tailVal, tailStart, flags);
    ce_cleanup<<<(NBOUND + 3) / 4, TPB, 0, stream>>>(h2, out,
                                                     headKey, headVal, headEnd,
                                                     tailKey, tailVal, tailStart);
    ce_repair<<<NBLK / 32, TPB, 0, stream>>>(h2, q, mol, out, flags);
}

// Round 18
// 36.713 us; speedup vs baseline: 1.8622x; 1.0550x over previous
//
#include <hip/hip_runtime.h>

#define N_ATOMS 8388608
#define N_MOLS  262144
#define N_PAIRS (N_ATOMS / 2)          // 4194304
#define TPB     256
#define PPB     512                    // pairs per block (2 per thread)
#define APB     1024                   // atoms per block
#define NBLK    (N_PAIRS / PPB)        // 8192 blocks
#define NBOUND  (NBLK - 1)             // 8191 boundaries
#define BINS    192                    // block mol-span ~32 typical + slack

// DPP cross-lane helpers (VALU-only). Masked/invalid lanes keep old value:
// key old=-1 (never matches), value old=0.
template<int CTRL, int RM>
__device__ __forceinline__ int dpp_key(int v) {
    return __builtin_amdgcn_update_dpp(-1, v, CTRL, RM, 0xf, false);
}
template<int CTRL, int RM>
__device__ __forceinline__ float dpp_val(float v) {
    return __int_as_float(
        __builtin_amdgcn_update_dpp(0, __float_as_int(v), CTRL, RM, 0xf, false));
}

// Main kernel: per-block segment sums entirely in LDS bins, then t, then a
// dense unconditional coalesced output write for every atom. No global
// scatter, no global atomics, no global memset dependencies.
__global__ __launch_bounds__(TPB) void ce_main(
    const float4* __restrict__ h4, const float2* __restrict__ q2,
    const int2* __restrict__ mol2, float2* __restrict__ out2,
    int* __restrict__ headKey, float2* __restrict__ headVal,
    int* __restrict__ headEnd,
    int* __restrict__ tailKey, float2* __restrict__ tailVal,
    int* __restrict__ tailStart, int* __restrict__ flags)
{
    __shared__ float bq[BINS], bs[BINS];
    __shared__ int sFirst, sLast, sHeadEnd, sTailStart;

    const int t = threadIdx.x;
    const int lane = t & 63;
    const int B = blockIdx.x;
    const int pbase = B * PPB;
    const int p0 = pbase + t, p1 = pbase + TPB + t;

    // issue all global loads first (latency overlap with LDS init)
    float4 h0 = h4[p0], h1 = h4[p1];
    float2 q0 = q2[p0], q1 = q2[p1];
    int2   m0 = mol2[p0], m1 = mol2[p1];

    if (t < BINS) { bq[t] = 0.f; bs[t] = 0.f; }
    if (t == 0) { sFirst = m0.x; sHeadEnd = -1; sTailStart = 0x7fffffff; }
    if (t == TPB - 1) sLast = m1.y;
    __syncthreads();
    const int mF = sFirst, mL = sLast;
    const bool bad = (mL - mF >= BINS);   // id-gap overflow, P ~ 0; repair net below

    float si00, esi00, si01, esi01, si10, esi10, si11, esi11;

#define CHUNK(hv, qv, mv, PIDX, SI0, ESI0, SI1, ESI1)                        \
    {                                                                        \
        float si0 = 1.0f / hv.y, si1 = 1.0f / hv.w;                          \
        float esi0 = hv.x * si0, esi1 = hv.z * si1;                          \
        float qe0 = qv.x + esi0, qe1 = qv.y + esi1;                          \
        bool  b = (mv.x != mv.y);                                            \
        int   key = mv.y;                                                    \
        float pq = b ? qe1 : (qe0 + qe1);                                    \
        float ps = b ? si1 : (si0 + si1);                                    \
        if (b) {                                                             \
            int idx = min(mv.x - mF, BINS - 1);                              \
            atomicAdd(&bq[idx], qe0); atomicAdd(&bs[idx], si0);              \
        }                                                                    \
        SCAN_STEP(0x111, 0xf) SCAN_STEP(0x112, 0xf)                          \
        SCAN_STEP(0x114, 0xf) SCAN_STEP(0x118, 0xf)                          \
        SCAN_STEP(0x142, 0xa) SCAN_STEP(0x143, 0xc)                          \
        int  nk = __shfl_down(key, 1, 64);                                   \
        bool tail = (lane == 63) || (nk != key);                             \
        if (tail) {                                                          \
            int idx = min(key - mF, BINS - 1);                               \
            atomicAdd(&bq[idx], pq); atomicAdd(&bs[idx], ps);                \
        }                                                                    \
        int a0 = (PIDX) * 2;                                                 \
        if (mv.y == mF)      atomicMax(&sHeadEnd, a0 + 1);                   \
        else if (mv.x == mF) atomicMax(&sHeadEnd, a0);                       \
        if (mv.x == mL)      atomicMin(&sTailStart, a0);                     \
        else if (mv.y == mL) atomicMin(&sTailStart, a0 + 1);                 \
        SI0 = si0; ESI0 = esi0; SI1 = si1; ESI1 = esi1;                      \
    }
#define SCAN_STEP(CTRL, RM)                                                  \
    {                                                                        \
        int   k  = dpp_key<CTRL, RM>(key);                                   \
        float vq = dpp_val<CTRL, RM>(pq);                                    \
        float vs = dpp_val<CTRL, RM>(ps);                                    \
        if (k == key) { pq += vq; ps += vs; }                                \
    }

    CHUNK(h0, q0, m0, p0, si00, esi00, si01, esi01)
    CHUNK(h1, q1, m1, p1, si10, esi10, si11, esi11)
#undef SCAN_STEP
#undef CHUNK

    __syncthreads();
    // export records (bq/bs reads land before the divide overwrites them)
    if (t == 0) {
        headKey[B] = mF;
        headVal[B] = make_float2(bq[0], bs[0]);
        headEnd[B] = sHeadEnd;
        flags[B]   = bad ? 1 : 0;
    }
    if (t == 64) {
        int li = min(mL - mF, BINS - 1);
        tailKey[B]   = mL;
        tailVal[B]   = make_float2(bq[li], bs[li]);
        tailStart[B] = sTailStart;
    }
    __syncthreads();
    if (t < BINS) bq[t] = bq[t] / bs[t];   // per-bin t (unused bins never read)
    __syncthreads();

    int i00 = min(m0.x - mF, BINS - 1), i01 = min(m0.y - mF, BINS - 1);
    int i10 = min(m1.x - mF, BINS - 1), i11 = min(m1.y - mF, BINS - 1);
    out2[p0] = make_float2(bq[i00] * si00 - esi00, bq[i01] * si01 - esi01);
    out2[p1] = make_float2(bq[i10] * si10 - esi10, bq[i11] * si11 - esi11);
}

// Fused fixup kernel.
// Role A (4 boundaries/block): merge the straddling molecule's records along
// its chain and rewrite its atoms. Skips any chain touching a flagged block
// (repair is then the sole writer, so no intra-kernel race).
// Role B (4 flag slots/block): pathological-gap repair, direct walk.
__global__ __launch_bounds__(TPB) void ce_fixup(
    const float2* __restrict__ h2, const float* __restrict__ q,
    const int* __restrict__ mol, float* __restrict__ out,
    const int* __restrict__ headKey, const float2* __restrict__ headVal,
    const int* __restrict__ headEnd,
    const int* __restrict__ tailKey, const float2* __restrict__ tailVal,
    const int* __restrict__ tailStart, const int* __restrict__ flags)
{
    // ---- Role A: boundary cleanup ----
    {
        int i = blockIdx.x * 4 + (threadIdx.x >> 6);   // boundary id
        int lane = threadIdx.x & 63;
        if (i < NBOUND) {
            int M = tailKey[i];
            bool skip = flags[i] || flags[i + 1];
            if (!skip && headKey[i + 1] == M &&
                !(headKey[i] == M && i > 0 && tailKey[i - 1] == M)) {
                float2 tot = tailVal[i];
                int start = tailStart[i];
                int j = i + 1;
                float2 hv1 = headVal[j];
                tot.x += hv1.x; tot.y += hv1.y;
                bool chainBad = false;
                while (j < NBOUND && tailKey[j] == M && headKey[j + 1] == M) {
                    ++j;
                    if (flags[j]) chainBad = true;
                    float2 hvj = headVal[j];
                    tot.x += hvj.x; tot.y += hvj.y;
                }
                if (j < NBLK && flags[j]) chainBad = true;
                if (!chainBad) {
                    int end = headEnd[j];
                    float tt = tot.x / tot.y;
                    for (int a = start + lane; a <= end; a += 64) {
                        float2 hv = h2[a];
                        out[a] = (tt - hv.x) / hv.y;
                    }
                }
            }
        }
    }

    // ---- Role B: pathological repair (flags never set in practice) ----
    for (int fb = blockIdx.x * 4; fb < blockIdx.x * 4 + 4 && fb < NBLK; ++fb) {
        if (!flags[fb]) continue;
        int bStart = fb * APB;
        if (threadIdx.x == 0) {
            int s = bStart;
            while (s > 0 && mol[s - 1] == mol[bStart]) --s;
            if (s < bStart) {
                int m = mol[s];
                float sq = 0.f, ss = 0.f; int e = s;
                for (int x = s; x < N_ATOMS && mol[x] == m; ++x) {
                    float2 hv = h2[x]; float si = 1.0f / hv.y;
                    sq += q[x] + hv.x * si; ss += si; e = x;
                }
                float tt = sq / ss;
                for (int x = s; x <= e; ++x) {
                    float2 hv = h2[x]; out[x] = (tt - hv.x) / hv.y;
                }
            }
        }
        for (int a = bStart + threadIdx.x; a < bStart + APB; a += TPB) {
            if (a != 0 && mol[a - 1] == mol[a]) continue;   // not a mol start
            int m = mol[a];
            float sq = 0.f, ss = 0.f; int e = a;
            for (int x = a; x < N_ATOMS && mol[x] == m; ++x) {
                float2 hv = h2[x]; float si = 1.0f / hv.y;
                sq += q[x] + hv.x * si; ss += si; e = x;
            }
            float tt = sq / ss;
            for (int x = a; x <= e; ++x) {
                float2 hv = h2[x]; out[x] = (tt - hv.x) / hv.y;
            }
        }
    }
}

extern "C" void kernel_launch(void* const* d_in, const int* in_sizes, int n_in,
                              void* d_out, int out_size, void* d_ws, size_t ws_size,
                              hipStream_t stream) {
    const float4* h4   = (const float4*)d_in[0];
    const float2* h2   = (const float2*)d_in[0];
    const float*  q    = (const float*)d_in[1];
    const float2* q2   = (const float2*)d_in[1];
    const int*    mol  = (const int*)d_in[2];
    const int2*   mol2 = (const int2*)d_in[2];
    float2* out2 = (float2*)d_out;
    float*  out  = (float*)d_out;

    // ws layout (8-byte-aligned entries first)
    float2* headVal   = (float2*)d_ws;                 // 64 KB
    float2* tailVal   = headVal + NBLK;                // 64 KB
    int*    headKey   = (int*)(tailVal + NBLK);        // 32 KB
    int*    tailKey   = headKey + NBLK;                // 32 KB
    int*    headEnd   = tailKey + NBLK;                // 32 KB
    int*    tailStart = headEnd + NBLK;                // 32 KB
    int*    flags     = tailStart + NBLK;              // 32 KB

    ce_main<<<NBLK, TPB, 0, stream>>>(h4, q2, mol2, out2,
                                      headKey, headVal, headEnd,
                                      tailKey, tailVal, tailStart, flags);
    ce_fixup<<<(NBOUND + 3) / 4, TPB, 0, stream>>>(h2, q, mol, out,
                                                   headKey, headVal, headEnd,
                                                   tailKey, tailVal, tailStart,
                                                   flags);
}

// Round 19
// 36.559 us; speedup vs baseline: 1.8700x; 1.0042x over previous
//
#include <hip/hip_runtime.h>

#define N_ATOMS 8388608
#define N_MOLS  262144
#define N_PAIRS (N_ATOMS / 2)          // 4194304
#define TPB     256
#define CPT     4                      // pair-chunks per thread
#define PPB     (TPB * CPT)            // 1024 pairs per block
#define APB     (PPB * 2)              // 2048 atoms per block
#define NBLK    (N_PAIRS / PPB)        // 4096 blocks
#define NBOUND  (NBLK - 1)             // 4095 boundaries
#define BINS    256                    // block mol-span ~64 typical + slack

// DPP cross-lane helpers (VALU-only). Masked/invalid lanes keep old value:
// key old=-1 (never matches), value old=0.
template<int CTRL, int RM>
__device__ __forceinline__ int dpp_key(int v) {
    return __builtin_amdgcn_update_dpp(-1, v, CTRL, RM, 0xf, false);
}
template<int CTRL, int RM>
__device__ __forceinline__ float dpp_val(float v) {
    return __int_as_float(
        __builtin_amdgcn_update_dpp(0, __float_as_int(v), CTRL, RM, 0xf, false));
}

// Main kernel: per-block segment sums entirely in LDS bins, then t, then a
// dense unconditional coalesced output write for every atom. No global
// scatter, no global atomics, no global memset dependencies.
// 4 pair-chunks per thread amortize bin init/divide/export 2x over r18 and
// give 4 independent DPP scan chains for ILP.
__global__ __launch_bounds__(TPB) void ce_main(
    const float4* __restrict__ h4, const float2* __restrict__ q2,
    const int2* __restrict__ mol2, float2* __restrict__ out2,
    int* __restrict__ headKey, float2* __restrict__ headVal,
    int* __restrict__ headEnd,
    int* __restrict__ tailKey, float2* __restrict__ tailVal,
    int* __restrict__ tailStart, int* __restrict__ flags)
{
    __shared__ float bq[BINS], bs[BINS];
    __shared__ int sFirst, sLast, sHeadEnd, sTailStart;

    const int t = threadIdx.x;
    const int lane = t & 63;
    const int B = blockIdx.x;
    const int pbase = B * PPB;
    const int p0 = pbase + t,           p1 = pbase + TPB + t;
    const int p2 = pbase + 2 * TPB + t, p3 = pbase + 3 * TPB + t;

    // issue all global loads first (latency overlap with LDS init)
    float4 h0 = h4[p0], h1 = h4[p1], h2v = h4[p2], h3 = h4[p3];
    float2 q0 = q2[p0], q1 = q2[p1], q2v = q2[p2], q3 = q2[p3];
    int2   m0 = mol2[p0], m1 = mol2[p1], m2 = mol2[p2], m3 = mol2[p3];

    if (t < BINS) { bq[t] = 0.f; bs[t] = 0.f; }
    if (t == 0) { sFirst = m0.x; sHeadEnd = -1; sTailStart = 0x7fffffff; }
    if (t == TPB - 1) sLast = m3.y;
    __syncthreads();
    const int mF = sFirst, mL = sLast;
    const bool bad = (mL - mF >= BINS);   // id-gap overflow, P ~ 0; repair net

    float si00, esi00, si01, esi01, si10, esi10, si11, esi11;
    float si20, esi20, si21, esi21, si30, esi30, si31, esi31;

#define CHUNK(hv, qv, mv, PIDX, SI0, ESI0, SI1, ESI1)                        \
    {                                                                        \
        float si0 = 1.0f / hv.y, si1 = 1.0f / hv.w;                          \
        float esi0 = hv.x * si0, esi1 = hv.z * si1;                          \
        float qe0 = qv.x + esi0, qe1 = qv.y + esi1;                          \
        bool  b = (mv.x != mv.y);                                            \
        int   key = mv.y;                                                    \
        float pq = b ? qe1 : (qe0 + qe1);                                    \
        float ps = b ? si1 : (si0 + si1);                                    \
        if (b) {                                                             \
            int idx = min(mv.x - mF, BINS - 1);                              \
            atomicAdd(&bq[idx], qe0); atomicAdd(&bs[idx], si0);              \
        }                                                                    \
        SCAN_STEP(0x111, 0xf) SCAN_STEP(0x112, 0xf)                          \
        SCAN_STEP(0x114, 0xf) SCAN_STEP(0x118, 0xf)                          \
        SCAN_STEP(0x142, 0xa) SCAN_STEP(0x143, 0xc)                          \
        int  nk = __shfl_down(key, 1, 64);                                   \
        bool tail = (lane == 63) || (nk != key);                             \
        if (tail) {                                                          \
            int idx = min(key - mF, BINS - 1);                               \
            atomicAdd(&bq[idx], pq); atomicAdd(&bs[idx], ps);                \
        }                                                                    \
        int a0 = (PIDX) * 2;                                                 \
        if (mv.y == mF)      atomicMax(&sHeadEnd, a0 + 1);                   \
        else if (mv.x == mF) atomicMax(&sHeadEnd, a0);                       \
        if (mv.x == mL)      atomicMin(&sTailStart, a0);                     \
        else if (mv.y == mL) atomicMin(&sTailStart, a0 + 1);                 \
        SI0 = si0; ESI0 = esi0; SI1 = si1; ESI1 = esi1;                      \
    }
#define SCAN_STEP(CTRL, RM)                                                  \
    {                                                                        \
        int   k  = dpp_key<CTRL, RM>(key);                                   \
        float vq = dpp_val<CTRL, RM>(pq);                                    \
        float vs = dpp_val<CTRL, RM>(ps);                                    \
        if (k == key) { pq += vq; ps += vs; }                                \
    }

    CHUNK(h0,  q0,  m0, p0, si00, esi00, si01, esi01)
    CHUNK(h1,  q1,  m1, p1, si10, esi10, si11, esi11)
    CHUNK(h2v, q2v, m2, p2, si20, esi20, si21, esi21)
    CHUNK(h3,  q3,  m3, p3, si30, esi30, si31, esi31)
#undef SCAN_STEP
#undef CHUNK

    __syncthreads();
    // export records (bq/bs reads land before the divide overwrites them)
    if (t == 0) {
        headKey[B] = mF;
        headVal[B] = make_float2(bq[0], bs[0]);
        headEnd[B] = sHeadEnd;
        flags[B]   = bad ? 1 : 0;
    }
    if (t == 64) {
        int li = min(mL - mF, BINS - 1);
        tailKey[B]   = mL;
        tailVal[B]   = make_float2(bq[li], bs[li]);
        tailStart[B] = sTailStart;
    }
    __syncthreads();
    if (t < BINS) bq[t] = bq[t] / bs[t];   // per-bin t (unused bins never read)
    __syncthreads();

    int i00 = min(m0.x - mF, BINS - 1), i01 = min(m0.y - mF, BINS - 1);
    int i10 = min(m1.x - mF, BINS - 1), i11 = min(m1.y - mF, BINS - 1);
    int i20 = min(m2.x - mF, BINS - 1), i21 = min(m2.y - mF, BINS - 1);
    int i30 = min(m3.x - mF, BINS - 1), i31 = min(m3.y - mF, BINS - 1);
    out2[p0] = make_float2(bq[i00] * si00 - esi00, bq[i01] * si01 - esi01);
    out2[p1] = make_float2(bq[i10] * si10 - esi10, bq[i11] * si11 - esi11);
    out2[p2] = make_float2(bq[i20] * si20 - esi20, bq[i21] * si21 - esi21);
    out2[p3] = make_float2(bq[i30] * si30 - esi30, bq[i31] * si31 - esi31);
}

// Fused fixup kernel.
// Role A (4 boundaries/block): merge the straddling molecule's records along
// its chain and rewrite its atoms. Skips any chain touching a flagged block
// (repair is then the sole writer, so no intra-kernel race).
// Role B (4 flag slots/block): pathological-gap repair, direct walk.
__global__ __launch_bounds__(TPB) void ce_fixup(
    const float2* __restrict__ h2, const float* __restrict__ q,
    const int* __restrict__ mol, float* __restrict__ out,
    const int* __restrict__ headKey, const float2* __restrict__ headVal,
    const int* __restrict__ headEnd,
    const int* __restrict__ tailKey, const float2* __restrict__ tailVal,
    const int* __restrict__ tailStart, const int* __restrict__ flags)
{
    // ---- Role A: boundary cleanup ----
    {
        int i = blockIdx.x * 4 + (threadIdx.x >> 6);   // boundary id
        int lane = threadIdx.x & 63;
        if (i < NBOUND) {
            int M = tailKey[i];
            bool skip = flags[i] || flags[i + 1];
            if (!skip && headKey[i + 1] == M &&
                !(headKey[i] == M && i > 0 && tailKey[i - 1] == M)) {
                float2 tot = tailVal[i];
                int start = tailStart[i];
                int j = i + 1;
                float2 hv1 = headVal[j];
                tot.x += hv1.x; tot.y += hv1.y;
                bool chainBad = false;
                while (j < NBOUND && tailKey[j] == M && headKey[j + 1] == M) {
                    ++j;
                    if (flags[j]) chainBad = true;
                    float2 hvj = headVal[j];
                    tot.x += hvj.x; tot.y += hvj.y;
                }
                if (j < NBLK && flags[j]) chainBad = true;
                if (!chainBad) {
                    int end = headEnd[j];
                    float tt = tot.x / tot.y;
                    for (int a = start + lane; a <= end; a += 64) {
                        float2 hv = h2[a];
                        out[a] = (tt - hv.x) / hv.y;
                    }
                }
            }
        }
    }

    // ---- Role B: pathological repair (flags never set in practice) ----
    for (int fb = blockIdx.x * 4; fb < blockIdx.x * 4 + 4 && fb < NBLK; ++fb) {
        if (!flags[fb]) continue;
        int bStart = fb * APB;
        if (threadIdx.x == 0) {
            int s = bStart;
            while (s > 0 && mol[s - 1] == mol[bStart]) --s;
            if (s < bStart) {
                int m = mol[s];
                float sq = 0.f, ss = 0.f; int e = s;
                for (int x = s; x < N_ATOMS && mol[x] == m; ++x) {
                    float2 hv = h2[x]; float si = 1.0f / hv.y;
                    sq += q[x] + hv.x * si; ss += si; e = x;
                }
                float tt = sq / ss;
                for (int x = s; x <= e; ++x) {
                    float2 hv = h2[x]; out[x] = (tt - hv.x) / hv.y;
                }
            }
        }
        for (int a = bStart + threadIdx.x; a < bStart + APB; a += TPB) {
            if (a != 0 && mol[a - 1] == mol[a]) continue;   // not a mol start
            int m = mol[a];
            float sq = 0.f, ss = 0.f; int e = a;
            for (int x = a; x < N_ATOMS && mol[x] == m; ++x) {
                float2 hv = h2[x]; float si = 1.0f / hv.y;
                sq += q[x] + hv.x * si; ss += si; e = x;
            }
            float tt = sq / ss;
            for (int x = a; x <= e; ++x) {
                float2 hv = h2[x]; out[x] = (tt - hv.x) / hv.y;
            }
        }
    }
}

extern "C" void kernel_launch(void* const* d_in, const int* in_sizes, int n_in,
                              void* d_out, int out_size, void* d_ws, size_t ws_size,
                              hipStream_t stream) {
    const float4* h4   = (const float4*)d_in[0];
    const float2* h2   = (const float2*)d_in[0];
    const float*  q    = (const float*)d_in[1];
    const float2* q2   = (const float2*)d_in[1];
    const int*    mol  = (const int*)d_in[2];
    const int2*   mol2 = (const int2*)d_in[2];
    float2* out2 = (float2*)d_out;
    float*  out  = (float*)d_out;

    // ws layout (8-byte-aligned entries first)
    float2* headVal   = (float2*)d_ws;                 // 32 KB
    float2* tailVal   = headVal + NBLK;                // 32 KB
    int*    headKey   = (int*)(tailVal + NBLK);        // 16 KB
    int*    tailKey   = headKey + NBLK;                // 16 KB
    int*    headEnd   = tailKey + NBLK;                // 16 KB
    int*    tailStart = headEnd + NBLK;                // 16 KB
    int*    flags     = tailStart + NBLK;              // 16 KB

    ce_main<<<NBLK, TPB, 0, stream>>>(h4, q2, mol2, out2,
                                      headKey, headVal, headEnd,
                                      tailKey, tailVal, tailStart, flags);
    ce_fixup<<<(NBOUND + 3) / 4, TPB, 0, stream>>>(h2, q, mol, out,
                                                   headKey, headVal, headEnd,
                                                   tailKey, tailVal, tailStart,
                                                   flags);
}